// Round 4
// baseline (326.312 us; speedup 1.0000x reference)
//
#include <hip/hip_runtime.h>
#include <hip/hip_cooperative_groups.h>

namespace cg = cooperative_groups;

#define NR    8192
#define ALPHA 0.2f

__device__ inline void scan256(float* __restrict__ g, int stride, float* __restrict__ s)
{
    const int t = threadIdx.x;
    const float v = g[t * stride];
    s[t] = v;
    __syncthreads();
    for (int off = 1; off < 256; off <<= 1) {
        float u = (t >= off) ? s[t - off] : 0.f;
        __syncthreads();
        s[t] += u;
        __syncthreads();
    }
    g[t * stride] = (t > 0) ? s[t - 1] : 0.f;
    if (t == 255) g[256 * stride] = s[255];
    __syncthreads();
}

// One cooperative kernel, 512 blocks x 256 threads (2 blocks/CU), 5 grid syncs.
// Phase A: H = X@W, f1, f2, per-block f2-max          (each block: 16 rows)
// Phase B: rank partials (32 j-tiles x 16 k-slices)   (plain stores)
// Phase C: global max + scatter into rank order + P/Q (blocks 0..31)
// Phase D: per-chunk (32 ranks) sums of P*h, Q*h      (blocks 0..255)
// Phase E: exclusive scan over 256 chunks             (blocks 0..64)
// Phase F: per-row bsearch (LDS) + <=32-term fix + elu(each block: 16 rows)
__global__ __launch_bounds__(256) void fused(
    const float* __restrict__ X, const float* __restrict__ W, const float* __restrict__ aa,
    float* __restrict__ H, float* __restrict__ F1, float* __restrict__ F2,
    float* __restrict__ BMAX, unsigned* __restrict__ RANKP, float* __restrict__ FMf,
    float* __restrict__ SF2, int* __restrict__ PERM, float* __restrict__ PS,
    float* __restrict__ QS, float* __restrict__ CHP, float* __restrict__ CHQ,
    float* __restrict__ chp, float* __restrict__ chq, float* __restrict__ OUT)
{
    cg::grid_group grid = cg::this_grid();
    __shared__ union {
        struct { float xs[16 * 128]; float part[16 * 4 * 64]; float wmax[4]; } pa; // 24.6 KB
        struct { float f2s[512]; } pb;
        struct { float sm[256]; } pc;
        struct { float redP[256], redQ[256], reds[8]; } pd;
        struct { float s[256]; } pe;
        struct { float sf2[NR]; } pf;                                              // 32 KB
    } u;

    const int tid = threadIdx.x;
    const int w = tid >> 6, c = tid & 63;
    const int bid = blockIdx.x;

    // ---------------- Phase A ----------------
    {
        const int R0 = bid * 16;
        float Wreg[32];
#pragma unroll
        for (int e = 0; e < 32; ++e) Wreg[e] = W[(w * 32 + e) * 64 + c];
#pragma unroll
        for (int q = 0; q < 8; ++q) { int idx = q * 256 + tid; u.pa.xs[idx] = X[R0 * 128 + idx]; }
        __syncthreads();

        for (int r = 0; r < 16; ++r) {
            float acc = 0.f;
            const float* xr = &u.pa.xs[r * 128 + w * 32];
#pragma unroll
            for (int e = 0; e < 32; ++e) acc = fmaf(xr[e], Wreg[e], acc);
            u.pa.part[(r * 4 + w) * 64 + c] = acc;
        }
        __syncthreads();

        const float a1 = aa[c], a2 = aa[64 + c];
        float lmax = -3.0e38f;
        for (int rr = 0; rr < 4; ++rr) {
            const int r = w * 4 + rr;
            const int i = R0 + r;
            float h = u.pa.part[(r * 4 + 0) * 64 + c] + u.pa.part[(r * 4 + 1) * 64 + c]
                    + u.pa.part[(r * 4 + 2) * 64 + c] + u.pa.part[(r * 4 + 3) * 64 + c];
            H[i * 64 + c] = h;
            float v1 = h * a1, v2 = h * a2;
#pragma unroll
            for (int m = 32; m >= 1; m >>= 1) {
                v1 += __shfl_xor(v1, m, 64);
                v2 += __shfl_xor(v2, m, 64);
            }
            if (c == 0) { F1[i] = v1; F2[i] = v2; }
            lmax = fmaxf(lmax, v2);
        }
        if (c == 0) u.pa.wmax[w] = lmax;
        __syncthreads();
        if (tid == 0)
            BMAX[bid] = fmaxf(fmaxf(u.pa.wmax[0], u.pa.wmax[1]), fmaxf(u.pa.wmax[2], u.pa.wmax[3]));
    }
    grid.sync();

    // ---------------- Phase B ----------------
    {
        const int bj = bid & 31, bk = bid >> 5;       // 32 j-tiles x 16 k-slices
        const int j = bj * 256 + tid;
        const float th = F2[j];
        for (int q = 0; q < 2; ++q) u.pb.f2s[q * 256 + tid] = F2[bk * 512 + q * 256 + tid];
        __syncthreads();
        unsigned cnt = 0;
        const int base = bk * 512;
        for (int q = 0; q < 128; ++q) {
            float4 v = ((float4*)u.pb.f2s)[q];
            int jj = base + q * 4;
            cnt += (unsigned)((v.x < th) | ((v.x == th) & ((jj + 0) < j)));
            cnt += (unsigned)((v.y < th) | ((v.y == th) & ((jj + 1) < j)));
            cnt += (unsigned)((v.z < th) | ((v.z == th) & ((jj + 2) < j)));
            cnt += (unsigned)((v.w < th) | ((v.w == th) & ((jj + 3) < j)));
        }
        RANKP[bk * NR + j] = cnt;
    }
    grid.sync();

    // ---------------- Phase C ----------------
    if (bid < 32) {
        u.pc.sm[tid] = fmaxf(BMAX[tid], BMAX[256 + tid]);
        __syncthreads();
        for (int off = 128; off > 0; off >>= 1) {
            if (tid < off) u.pc.sm[tid] = fmaxf(u.pc.sm[tid], u.pc.sm[tid + off]);
            __syncthreads();
        }
        const float fm = u.pc.sm[0];
        const int j = bid * 256 + tid;
        unsigned r = 0;
#pragma unroll
        for (int s = 0; s < 16; ++s) r += RANKP[s * NR + j];
        const float f = F2[j];
        const float d = f - fm;
        SF2[r] = f;
        PERM[r] = j;
        PS[r] = expf(d);
        QS[r] = expf(ALPHA * d);
        if (bid == 0 && tid == 0) FMf[0] = fm;
    }
    grid.sync();

    // ---------------- Phase D ----------------
    if (bid < 256) {
        float accP = 0.f, accQ = 0.f, sp = 0.f, sq = 0.f;
        for (int e = 0; e < 8; ++e) {
            const int t = bid * 32 + w * 8 + e;
            const int j = PERM[t];
            const float P = PS[t], Q = QS[t];
            const float hv = H[j * 64 + c];
            accP = fmaf(P, hv, accP);
            accQ = fmaf(Q, hv, accQ);
            sp += P; sq += Q;
        }
        u.pd.redP[w * 64 + c] = accP;
        u.pd.redQ[w * 64 + c] = accQ;
        if (c == 0) { u.pd.reds[w] = sp; u.pd.reds[4 + w] = sq; }
        __syncthreads();
        if (w == 0) {
            float p = u.pd.redP[c] + u.pd.redP[64 + c] + u.pd.redP[128 + c] + u.pd.redP[192 + c];
            float q = u.pd.redQ[c] + u.pd.redQ[64 + c] + u.pd.redQ[128 + c] + u.pd.redQ[192 + c];
            CHP[bid * 64 + c] = p;
            CHQ[bid * 64 + c] = q;
            if (c == 0) {
                chp[bid] = u.pd.reds[0] + u.pd.reds[1] + u.pd.reds[2] + u.pd.reds[3];
                chq[bid] = u.pd.reds[4] + u.pd.reds[5] + u.pd.reds[6] + u.pd.reds[7];
            }
        }
    }
    grid.sync();

    // ---------------- Phase E ----------------
    if (bid < 64) {
        scan256(CHP + bid, 64, u.pe.s);
        scan256(CHQ + bid, 64, u.pe.s);
    } else if (bid == 64) {
        scan256(chp, 1, u.pe.s);
        scan256(chq, 1, u.pe.s);
    }
    grid.sync();

    // ---------------- Phase F ----------------
    {
#pragma unroll
        for (int q = 0; q < 32; ++q) u.pf.sf2[q * 256 + tid] = SF2[q * 256 + tid];
        __syncthreads();
        const float fm = FMf[0];
        const float Ptot = CHP[256 * 64 + c];
        const float ptot = chp[256];
        for (int rr = 0; rr < 4; ++rr) {
            const int i = bid * 16 + w * 4 + rr;
            const float f1 = F1[i];
            const float s = f1 + fm;
            const float m = fmaxf(s, ALPHA * s);
            const float A = expf(s - m);
            const float B = expf(ALPHA * s - m);
            const float th = -f1;

            int lo = 0, hi = NR;
            while (lo < hi) {
                int mid = (lo + hi) >> 1;
                if (u.pf.sf2[mid] < th) lo = mid + 1; else hi = mid;
            }
            const int t = lo;
            const int b = t >> 5, t0 = b << 5;

            float qv = CHQ[b * 64 + c];
            float pv = 0.f;
            float qs = chq[b], ps = 0.f;
            for (int tt = t0; tt < t; ++tt) {
                const int j = PERM[tt];
                const float P = PS[tt], Q = QS[tt];
                const float hv = H[j * 64 + c];
                qv = fmaf(Q, hv, qv);
                pv = fmaf(P, hv, pv);
                qs += Q; ps += P;
            }
            const float Pvec = Ptot - (CHP[b * 64 + c] + pv);
            const float pden = ptot - (chp[b] + ps);
            const float num = A * Pvec + B * qv;
            const float den = A * pden + B * qs;
            const float feat = num / den;
            OUT[i * 64 + c] = feat > 0.f ? feat : expm1f(feat);
        }
    }
}

extern "C" void kernel_launch(void* const* d_in, const int* in_sizes, int n_in,
                              void* d_out, int out_size, void* d_ws, size_t ws_size,
                              hipStream_t stream) {
    const float* X = (const float*)d_in[0];   // 8192 x 128
    const float* W = (const float*)d_in[1];   // 128 x 64
    const float* a = (const float*)d_in[2];   // 128 x 1
    float* OUT = (float*)d_out;               // 8192 x 64

    float* ws = (float*)d_ws;
    float*    H     = ws;                           // 524288
    float*    F1    = H + 524288;                   // 8192
    float*    F2    = F1 + 8192;                    // 8192
    unsigned* RANKP = (unsigned*)(F2 + 8192);       // 16 * 8192
    float*    BMAX  = (float*)(RANKP + 16 * 8192);  // 512
    float*    FMf   = BMAX + 512;                   // 16 (1 used)
    float*    SF2   = FMf + 16;                     // 8192
    int*      PERM  = (int*)(SF2 + 8192);           // 8192
    float*    PS    = (float*)(PERM + 8192);        // 8192
    float*    QS    = PS + 8192;                    // 8192
    float*    CHP   = QS + 8192;                    // 257*64
    float*    CHQ   = CHP + 257 * 64;               // 257*64
    float*    chp   = CHQ + 257 * 64;               // 257
    float*    chq   = chp + 257;                    // 257

    void* args[] = { &X, &W, &a, &H, &F1, &F2, &BMAX, &RANKP, &FMf,
                     &SF2, &PERM, &PS, &QS, &CHP, &CHQ, &chp, &chq, &OUT };
    hipLaunchCooperativeKernel((const void*)fused, dim3(512), dim3(256),
                               args, 0, stream);
}

// Round 5
// 66.474 us; speedup vs baseline: 4.9089x; 4.9089x over previous
//
#include <hip/hip_runtime.h>

#define NR    8192
#define ALPHA 0.2f

// K1 (A): h = X @ W, f1 = h@a1, f2 = h@a2, per-block f2-max (plain stores only).
__global__ __launch_bounds__(256) void k1_gemm(
    const float* __restrict__ X, const float* __restrict__ W, const float* __restrict__ a,
    float* __restrict__ H, float* __restrict__ F1, float* __restrict__ F2,
    float* __restrict__ BMAX)
{
    __shared__ __align__(16) float xs[32 * 128];     // 16 KB
    __shared__ float part[32 * 4 * 64];              // 32 KB
    __shared__ float wmax[4];
    const int tid = threadIdx.x;
    const int w = tid >> 6, c = tid & 63;
    const int R0 = blockIdx.x * 32;

    float Wreg[32];
#pragma unroll
    for (int e = 0; e < 32; ++e) Wreg[e] = W[(w * 32 + e) * 64 + c];
#pragma unroll
    for (int q = 0; q < 16; ++q) { int idx = q * 256 + tid; xs[idx] = X[R0 * 128 + idx]; }
    __syncthreads();

    for (int r = 0; r < 32; ++r) {
        float acc = 0.f;
        const float* xr = &xs[r * 128 + w * 32];
#pragma unroll
        for (int e = 0; e < 32; ++e) acc = fmaf(xr[e], Wreg[e], acc);
        part[(r * 4 + w) * 64 + c] = acc;
    }
    __syncthreads();

    const float a1 = a[c], a2 = a[64 + c];
    float lmax = -3.0e38f;
    for (int rr = 0; rr < 8; ++rr) {
        const int r = w * 8 + rr;
        const int i = R0 + r;
        float h = part[(r * 4 + 0) * 64 + c] + part[(r * 4 + 1) * 64 + c]
                + part[(r * 4 + 2) * 64 + c] + part[(r * 4 + 3) * 64 + c];
        H[i * 64 + c] = h;
        float v1 = h * a1, v2 = h * a2;
#pragma unroll
        for (int m = 32; m >= 1; m >>= 1) {
            v1 += __shfl_xor(v1, m, 64);
            v2 += __shfl_xor(v2, m, 64);
        }
        if (c == 0) { F1[i] = v1; F2[i] = v2; }
        lmax = fmaxf(lmax, v2);
    }
    if (c == 0) wmax[w] = lmax;
    __syncthreads();
    if (tid == 0)
        BMAX[blockIdx.x] = fmaxf(fmaxf(wmax[0], wmax[1]), fmaxf(wmax[2], wmax[3]));
}

// K2 (B+C fused): each block stages full F2 (XOR-swizzled float4 -> the 8
// slice-groups read 8 distinct banks), computes exact tie-broken ranks for its
// 32 j's (1024 compares/thread), reduces BMAX -> fm, scatters + P/Q factors.
__global__ __launch_bounds__(256) void k2_rank_scatter(
    const float* __restrict__ F2v, const float* __restrict__ BMAX,
    float* __restrict__ SF2, int* __restrict__ PERM,
    float* __restrict__ PS, float* __restrict__ QS, float* __restrict__ FMf)
{
    __shared__ __align__(16) float f2s[NR];   // 32 KB (swizzled float4s)
    __shared__ unsigned cnts[256];            // [s][jj]
    __shared__ float sm[256];
    const int tid = threadIdx.x;
    const float4* F4 = (const float4*)F2v;
    float4* S4 = (float4*)f2s;

#pragma unroll
    for (int q0 = 0; q0 < 8; ++q0) {
        int g = q0 * 256 + tid;               // float4 index 0..2047
        S4[g ^ (g >> 8)] = F4[g];             // store swizzled (bijective per 256-slice)
    }
    sm[tid] = BMAX[tid];
    __syncthreads();
    for (int off = 128; off > 0; off >>= 1) {
        if (tid < off) sm[tid] = fmaxf(sm[tid], sm[tid + off]);
        __syncthreads();
    }
    const float fm = sm[0];

    const int jj = tid & 31, s = tid >> 5;
    const int j = blockIdx.x * 32 + jj;
    const int j4 = j >> 2;
    float4 tv = S4[j4 ^ (j4 >> 8)];
    const int jm = j & 3;
    const float th = jm == 0 ? tv.x : jm == 1 ? tv.y : jm == 2 ? tv.z : tv.w;

    unsigned cnt = 0;
    const int sbase = s * 1024;
    for (int q = 0; q < 256; ++q) {
        float4 v = S4[s * 256 + (q ^ s)];     // holds F4[s*256+q]; banks distinct per s
        int idx = sbase + q * 4;              // ORIGINAL element index
        cnt += (unsigned)((v.x < th) | ((v.x == th) & ((idx + 0) < j)));
        cnt += (unsigned)((v.y < th) | ((v.y == th) & ((idx + 1) < j)));
        cnt += (unsigned)((v.z < th) | ((v.z == th) & ((idx + 2) < j)));
        cnt += (unsigned)((v.w < th) | ((v.w == th) & ((idx + 3) < j)));
    }
    cnts[s * 32 + jj] = cnt;
    __syncthreads();

    if (tid < 32) {
        unsigned r = 0;
#pragma unroll
        for (int s2 = 0; s2 < 8; ++s2) r += cnts[s2 * 32 + tid];
        const int jG = blockIdx.x * 32 + tid;
        const int g4 = jG >> 2;
        float4 w4 = S4[g4 ^ (g4 >> 8)];
        const int gm = jG & 3;
        const float f = gm == 0 ? w4.x : gm == 1 ? w4.y : gm == 2 ? w4.z : w4.w;
        const float d = f - fm;
        SF2[r] = f;
        PERM[r] = jG;
        PS[r] = expf(d);
        QS[r] = expf(ALPHA * d);
    }
    if (blockIdx.x == 0 && tid == 0) FMf[0] = fm;
}

// K3 (D): per-chunk (32 ranks) sums of P*h, Q*h + scalar sums.
__global__ __launch_bounds__(256) void k3_chunks(
    const float* __restrict__ H, const int* __restrict__ PERM,
    const float* __restrict__ PS, const float* __restrict__ QS,
    float* __restrict__ CHP, float* __restrict__ CHQ,
    float* __restrict__ chp, float* __restrict__ chq)
{
    __shared__ float redP[256], redQ[256], reds[8];
    const int tid = threadIdx.x;
    const int w = tid >> 6, c = tid & 63;
    const int b = blockIdx.x;
    float accP = 0.f, accQ = 0.f, sp = 0.f, sq = 0.f;
    for (int e = 0; e < 8; ++e) {
        const int t = b * 32 + w * 8 + e;
        const int j = PERM[t];
        const float P = PS[t], Q = QS[t];
        const float hv = H[j * 64 + c];
        accP = fmaf(P, hv, accP);
        accQ = fmaf(Q, hv, accQ);
        sp += P; sq += Q;
    }
    redP[w * 64 + c] = accP;
    redQ[w * 64 + c] = accQ;
    if (c == 0) { reds[w] = sp; reds[4 + w] = sq; }
    __syncthreads();
    if (w == 0) {
        float p = redP[c] + redP[64 + c] + redP[128 + c] + redP[192 + c];
        float q = redQ[c] + redQ[64 + c] + redQ[128 + c] + redQ[192 + c];
        CHP[b * 64 + c] = p;
        CHQ[b * 64 + c] = q;
        if (c == 0) {
            chp[b] = reds[0] + reds[1] + reds[2] + reds[3];
            chq[b] = reds[4] + reds[5] + reds[6] + reds[7];
        }
    }
}

// K4 (E): exclusive scan over 256 chunks, totals at index 256.
__device__ void scan256(float* __restrict__ g, int stride, float* __restrict__ s)
{
    const int t = threadIdx.x;
    const float v = g[t * stride];
    s[t] = v;
    __syncthreads();
    for (int off = 1; off < 256; off <<= 1) {
        float u = (t >= off) ? s[t - off] : 0.f;
        __syncthreads();
        s[t] += u;
        __syncthreads();
    }
    g[t * stride] = (t > 0) ? s[t - 1] : 0.f;
    if (t == 255) g[256 * stride] = s[255];
    __syncthreads();
}

__global__ __launch_bounds__(256) void k4_scan(
    float* __restrict__ CHP, float* __restrict__ CHQ,
    float* __restrict__ chp, float* __restrict__ chq)
{
    __shared__ float s[256];
    const int b = blockIdx.x;
    if (b < 64) {
        scan256(CHP + b, 64, s);
        scan256(CHQ + b, 64, s);
    } else {
        scan256(chp, 1, s);
        scan256(chq, 1, s);
    }
}

// K6 (F): coarse 1KB LDS table (every 32nd sorted value) -> 8-step bsearch for
// the chunk, then UNIFORM predicated 32-iter correction (no exact boundary).
// 2048 blocks x 4 rows; only 1 KB LDS -> high occupancy.
__global__ __launch_bounds__(256) void k6_rows(
    const float* __restrict__ H, const float* __restrict__ F1,
    const float* __restrict__ FMf, const float* __restrict__ SF2,
    const int* __restrict__ PERM, const float* __restrict__ PS, const float* __restrict__ QS,
    const float* __restrict__ CHP, const float* __restrict__ CHQ,
    const float* __restrict__ chp, const float* __restrict__ chq,
    float* __restrict__ OUT)
{
    __shared__ float sb[256];
    const int tid = threadIdx.x;
    const int w = tid >> 6, c = tid & 63;
    sb[tid] = SF2[tid * 32];                  // first value of each chunk
    __syncthreads();

    const int i = blockIdx.x * 4 + w;
    const float fm = FMf[0];
    const float f1 = F1[i];
    const float s = f1 + fm;
    const float m = fmaxf(s, ALPHA * s);
    const float A = expf(s - m);
    const float B = expf(ALPHA * s - m);
    const float th = -f1;

    int lo = 0, hi = 256;                     // first chunk-start >= th
    while (lo < hi) { int mid = (lo + hi) >> 1; if (sb[mid] < th) lo = mid + 1; else hi = mid; }
    const int b = lo > 0 ? lo - 1 : 0;        // boundary t lies in [32b, 32(b+1)]
    const int t0 = b * 32;

    float qv = CHQ[b * 64 + c], pp = CHP[b * 64 + c];
    float qs = chq[b],          ps = chp[b];
    for (int tt = 0; tt < 32; ++tt) {
        const float sv = SF2[t0 + tt];
        const int jx = PERM[t0 + tt];
        const float P = PS[t0 + tt], Q = QS[t0 + tt];
        const float hv = H[jx * 64 + c];
        const bool cond = sv < th;            // exact per-element predicate
        const float cQ = cond ? Q : 0.f;
        const float cP = cond ? P : 0.f;
        qv = fmaf(cQ, hv, qv); qs += cQ;
        pp = fmaf(cP, hv, pp); ps += cP;
    }
    const float Pvec = CHP[256 * 64 + c] - pp;   // suffix P*h
    const float pden = chp[256] - ps;            // suffix P
    const float num = A * Pvec + B * qv;
    const float den = A * pden + B * qs;
    const float feat = num / den;
    OUT[i * 64 + c] = feat > 0.f ? feat : expm1f(feat);
}

extern "C" void kernel_launch(void* const* d_in, const int* in_sizes, int n_in,
                              void* d_out, int out_size, void* d_ws, size_t ws_size,
                              hipStream_t stream) {
    const float* X = (const float*)d_in[0];   // 8192 x 128
    const float* W = (const float*)d_in[1];   // 128 x 64
    const float* a = (const float*)d_in[2];   // 128 x 1
    float* OUT = (float*)d_out;               // 8192 x 64

    float* ws = (float*)d_ws;
    float* H    = ws;                         // 524288
    float* F1   = H + 524288;                 // 8192
    float* F2   = F1 + 8192;                  // 8192
    float* BMAX = F2 + 8192;                  // 256
    float* FMf  = BMAX + 256;                 // 16 (1 used)
    float* SF2  = FMf + 16;                   // 8192
    int*   PERM = (int*)(SF2 + 8192);         // 8192
    float* PS   = (float*)(PERM + 8192);      // 8192
    float* QS   = PS + 8192;                  // 8192
    float* CHP  = QS + 8192;                  // 257*64
    float* CHQ  = CHP + 257 * 64;             // 257*64
    float* chp  = CHQ + 257 * 64;             // 257
    float* chq  = chp + 257;                  // 257

    k1_gemm<<<256, 256, 0, stream>>>(X, W, a, H, F1, F2, BMAX);
    k2_rank_scatter<<<256, 256, 0, stream>>>(F2, BMAX, SF2, PERM, PS, QS, FMf);
    k3_chunks<<<256, 256, 0, stream>>>(H, PERM, PS, QS, CHP, CHQ, chp, chq);
    k4_scan<<<65, 256, 0, stream>>>(CHP, CHQ, chp, chq);
    k6_rows<<<2048, 256, 0, stream>>>(H, F1, FMf, SF2, PERM, PS, QS, CHP, CHQ, chp, chq, OUT);
}

// Round 6
// 63.389 us; speedup vs baseline: 5.1478x; 1.0487x over previous
//
#include <hip/hip_runtime.h>

#define NR    8192
#define ALPHA 0.2f

__device__ inline unsigned enc_f32(float f) {
    unsigned u = __float_as_uint(f);
    return (u & 0x80000000u) ? ~u : (u | 0x80000000u);
}
__device__ inline float dec_f32(unsigned u) {
    return __uint_as_float((u & 0x80000000u) ? (u ^ 0x80000000u) : ~u);
}

// K1: h = X @ W, f1 = h@a1, f2 = h@a2 stored as order-encoded uint key.
__global__ __launch_bounds__(256) void k1_gemm(
    const float* __restrict__ X, const float* __restrict__ W, const float* __restrict__ a,
    float* __restrict__ H, float* __restrict__ F1, unsigned* __restrict__ ENC)
{
    __shared__ __align__(16) float xs[32 * 128];     // 16 KB
    __shared__ float part[32 * 4 * 64];              // 32 KB
    const int tid = threadIdx.x;
    const int w = tid >> 6, c = tid & 63;
    const int R0 = blockIdx.x * 32;

    float Wreg[32];
#pragma unroll
    for (int e = 0; e < 32; ++e) Wreg[e] = W[(w * 32 + e) * 64 + c];
#pragma unroll
    for (int q = 0; q < 16; ++q) { int idx = q * 256 + tid; xs[idx] = X[R0 * 128 + idx]; }
    __syncthreads();

    for (int r = 0; r < 32; ++r) {
        float acc = 0.f;
        const float* xr = &xs[r * 128 + w * 32];
#pragma unroll
        for (int e = 0; e < 32; ++e) acc = fmaf(xr[e], Wreg[e], acc);
        part[(r * 4 + w) * 64 + c] = acc;
    }
    __syncthreads();

    const float a1 = a[c], a2 = a[64 + c];
    for (int rr = 0; rr < 8; ++rr) {
        const int r = w * 8 + rr;
        const int i = R0 + r;
        float h = part[(r * 4 + 0) * 64 + c] + part[(r * 4 + 1) * 64 + c]
                + part[(r * 4 + 2) * 64 + c] + part[(r * 4 + 3) * 64 + c];
        H[i * 64 + c] = h;
        float v1 = h * a1, v2 = h * a2;
#pragma unroll
        for (int m = 32; m >= 1; m >>= 1) {
            v1 += __shfl_xor(v1, m, 64);
            v2 += __shfl_xor(v2, m, 64);
        }
        if (c == 0) { F1[i] = v1; ENC[i] = enc_f32(v2); }
    }
}

// K2: stage all 8192 enc-keys in LDS (32 KB), compute exact tie-broken rank for
// this block's 16 j's (16 slices x 512 elems = 512 compares/thread), derive fm
// from the staged keys, scatter into rank order + P/Q factors.
// 512 blocks (2/CU) for TLP.
__global__ __launch_bounds__(256) void k2_rank_scatter(
    const unsigned* __restrict__ ENC,
    float* __restrict__ SF2, int* __restrict__ PERM,
    float* __restrict__ PS, float* __restrict__ QS, float* __restrict__ FMf)
{
    __shared__ __align__(16) unsigned ks[NR];   // 32 KB
    __shared__ unsigned red[256];
    __shared__ unsigned cnts[16 * 16];
    const int tid = threadIdx.x;
    const uint4* E4 = (const uint4*)ENC;
    uint4* K4 = (uint4*)ks;

    unsigned mx = 0;
#pragma unroll
    for (int q0 = 0; q0 < 8; ++q0) {
        uint4 v = E4[q0 * 256 + tid];
        K4[q0 * 256 + tid] = v;
        mx = max(max(mx, v.x), max(max(v.y, v.z), v.w));
    }
    red[tid] = mx;
    __syncthreads();
    for (int off = 128; off > 0; off >>= 1) {
        if (tid < off) red[tid] = max(red[tid], red[tid + off]);
        __syncthreads();
    }
    const float fm = dec_f32(red[0]);

    const int jj = tid & 15, s = tid >> 4;      // 16 j's x 16 slices
    const int j = blockIdx.x * 16 + jj;
    const unsigned th = ks[j];

    unsigned cnt = 0;
    for (int q = 0; q < 128; ++q) {
        uint4 v = K4[s * 128 + q];
        const int idx = s * 512 + q * 4;
        cnt += (unsigned)((v.x < th) | ((v.x == th) & ((idx + 0) < j)));
        cnt += (unsigned)((v.y < th) | ((v.y == th) & ((idx + 1) < j)));
        cnt += (unsigned)((v.z < th) | ((v.z == th) & ((idx + 2) < j)));
        cnt += (unsigned)((v.w < th) | ((v.w == th) & ((idx + 3) < j)));
    }
    cnts[s * 16 + jj] = cnt;
    __syncthreads();

    if (tid < 16) {
        unsigned r = 0;
#pragma unroll
        for (int s2 = 0; s2 < 16; ++s2) r += cnts[s2 * 16 + tid];
        const int jG = blockIdx.x * 16 + tid;
        const float f = dec_f32(ks[jG]);
        const float d = f - fm;
        SF2[r] = f;
        PERM[r] = jG;
        PS[r] = expf(d);
        QS[r] = expf(ALPHA * d);
    }
    if (blockIdx.x == 0 && tid == 0) FMf[0] = fm;
}

// K34 (chunk sums + scan fused): 65 blocks. Block c<64 owns output column c:
// thread t computes chunk t's sums of P*h and Q*h for column c (32 gathers),
// then in-LDS Hillis-Steele exclusive scan over the 256 chunks, totals at 256.
// Block 64: same for the scalar P/Q sums.
__global__ __launch_bounds__(256) void k34_chunkscan(
    const float* __restrict__ H, const int* __restrict__ PERM,
    const float* __restrict__ PS, const float* __restrict__ QS,
    float* __restrict__ CHP, float* __restrict__ CHQ,
    float* __restrict__ chp, float* __restrict__ chq)
{
    __shared__ float sP[256], sQ[256];
    const int t = threadIdx.x;
    const int cb = blockIdx.x;
    float accP = 0.f, accQ = 0.f;

    if (cb < 64) {
        const int4*   P4 = (const int4*)(PERM + t * 32);
        const float4* S4 = (const float4*)(PS + t * 32);
        const float4* Q4 = (const float4*)(QS + t * 32);
#pragma unroll
        for (int q = 0; q < 8; ++q) {
            int4   jv = P4[q];
            float4 pv = S4[q];
            float4 qv = Q4[q];
            accP = fmaf(pv.x, H[jv.x * 64 + cb], accP);
            accQ = fmaf(qv.x, H[jv.x * 64 + cb], accQ);
            accP = fmaf(pv.y, H[jv.y * 64 + cb], accP);
            accQ = fmaf(qv.y, H[jv.y * 64 + cb], accQ);
            accP = fmaf(pv.z, H[jv.z * 64 + cb], accP);
            accQ = fmaf(qv.z, H[jv.z * 64 + cb], accQ);
            accP = fmaf(pv.w, H[jv.w * 64 + cb], accP);
            accQ = fmaf(qv.w, H[jv.w * 64 + cb], accQ);
        }
    } else {
        const float4* S4 = (const float4*)(PS + t * 32);
        const float4* Q4 = (const float4*)(QS + t * 32);
#pragma unroll
        for (int q = 0; q < 8; ++q) {
            float4 pv = S4[q];
            float4 qv = Q4[q];
            accP += pv.x + pv.y + pv.z + pv.w;
            accQ += qv.x + qv.y + qv.z + qv.w;
        }
    }

    sP[t] = accP; sQ[t] = accQ;
    __syncthreads();
    for (int off = 1; off < 256; off <<= 1) {
        float uP = (t >= off) ? sP[t - off] : 0.f;
        float uQ = (t >= off) ? sQ[t - off] : 0.f;
        __syncthreads();
        sP[t] += uP; sQ[t] += uQ;
        __syncthreads();
    }
    const float eP = (t > 0) ? sP[t - 1] : 0.f;
    const float eQ = (t > 0) ? sQ[t - 1] : 0.f;
    if (cb < 64) {
        CHP[t * 64 + cb] = eP;
        CHQ[t * 64 + cb] = eQ;
        if (t == 255) { CHP[256 * 64 + cb] = sP[255]; CHQ[256 * 64 + cb] = sQ[255]; }
    } else {
        chp[t] = eP;
        chq[t] = eQ;
        if (t == 255) { chp[256] = sP[255]; chq[256] = sQ[255]; }
    }
}

// K6: coarse 1KB LDS table (chunk starts) -> 8-step bsearch, uniform predicated
// 32-iter exact correction, combine, elu. 2048 blocks x 4 rows.
__global__ __launch_bounds__(256) void k6_rows(
    const float* __restrict__ H, const float* __restrict__ F1,
    const float* __restrict__ FMf, const float* __restrict__ SF2,
    const int* __restrict__ PERM, const float* __restrict__ PS, const float* __restrict__ QS,
    const float* __restrict__ CHP, const float* __restrict__ CHQ,
    const float* __restrict__ chp, const float* __restrict__ chq,
    float* __restrict__ OUT)
{
    __shared__ float sb[256];
    const int tid = threadIdx.x;
    const int w = tid >> 6, c = tid & 63;
    sb[tid] = SF2[tid * 32];                  // first value of each chunk
    __syncthreads();

    const int i = blockIdx.x * 4 + w;
    const float fm = FMf[0];
    const float f1 = F1[i];
    const float s = f1 + fm;
    const float m = fmaxf(s, ALPHA * s);
    const float A = expf(s - m);
    const float B = expf(ALPHA * s - m);
    const float th = -f1;

    int lo = 0, hi = 256;                     // first chunk-start >= th
    while (lo < hi) { int mid = (lo + hi) >> 1; if (sb[mid] < th) lo = mid + 1; else hi = mid; }
    const int b = lo > 0 ? lo - 1 : 0;        // boundary lies within chunk b
    const int t0 = b * 32;

    float qv = CHQ[b * 64 + c], pp = CHP[b * 64 + c];
    float qs = chq[b],          ps = chp[b];
    for (int tt = 0; tt < 32; ++tt) {
        const float sv = SF2[t0 + tt];
        const int jx = PERM[t0 + tt];
        const float P = PS[t0 + tt], Q = QS[t0 + tt];
        const float hv = H[jx * 64 + c];
        const bool cond = sv < th;            // exact per-element predicate
        const float cQ = cond ? Q : 0.f;
        const float cP = cond ? P : 0.f;
        qv = fmaf(cQ, hv, qv); qs += cQ;
        pp = fmaf(cP, hv, pp); ps += cP;
    }
    const float Pvec = CHP[256 * 64 + c] - pp;   // suffix P*h
    const float pden = chp[256] - ps;            // suffix P
    const float num = A * Pvec + B * qv;
    const float den = A * pden + B * qs;
    const float feat = num / den;
    OUT[i * 64 + c] = feat > 0.f ? feat : expm1f(feat);
}

extern "C" void kernel_launch(void* const* d_in, const int* in_sizes, int n_in,
                              void* d_out, int out_size, void* d_ws, size_t ws_size,
                              hipStream_t stream) {
    const float* X = (const float*)d_in[0];   // 8192 x 128
    const float* W = (const float*)d_in[1];   // 128 x 64
    const float* a = (const float*)d_in[2];   // 128 x 1
    float* OUT = (float*)d_out;               // 8192 x 64

    float* ws = (float*)d_ws;
    float*    H    = ws;                         // 524288
    float*    F1   = H + 524288;                 // 8192
    unsigned* ENC  = (unsigned*)(F1 + 8192);     // 8192 (16B-aligned)
    float*    FMf  = (float*)(ENC + 8192);       // 16 (1 used)
    float*    SF2  = FMf + 16;                   // 8192
    int*      PERM = (int*)(SF2 + 8192);         // 8192
    float*    PS   = (float*)(PERM + 8192);      // 8192
    float*    QS   = PS + 8192;                  // 8192
    float*    CHP  = QS + 8192;                  // 257*64
    float*    CHQ  = CHP + 257 * 64;             // 257*64
    float*    chp  = CHQ + 257 * 64;             // 257
    float*    chq  = chp + 257;                  // 257

    k1_gemm<<<256, 256, 0, stream>>>(X, W, a, H, F1, ENC);
    k2_rank_scatter<<<512, 256, 0, stream>>>(ENC, SF2, PERM, PS, QS, FMf);
    k34_chunkscan<<<65, 256, 0, stream>>>(H, PERM, PS, QS, CHP, CHQ, chp, chq);
    k6_rows<<<2048, 256, 0, stream>>>(H, F1, FMf, SF2, PERM, PS, QS, CHP, CHQ, chp, chq, OUT);
}